// Round 1
// baseline (389.530 us; speedup 1.0000x reference)
//
#include <hip/hip_runtime.h>
#include <hip/hip_cooperative_groups.h>

namespace cg = cooperative_groups;

// B=16, S=2048, H=1024, C=4 kept rfft coeffs (ortho) == rank-7 projection:
//   a0 = sum_s x ; ak = sum_s x cos(2pi k s/S) ; bk = sum_s x sin(2pi k s/S), k=1..3
//   low[s] = (a0 + 2*sum_k(ak*cos + bk*sin)) / S
//   out = LayerNorm_H( (1+beta^2)*x + (1-beta^2)*low )
//
// v2: single cooperative kernel, 3 phases separated by grid.sync():
//   A: partial projection sums per (chunk,b)          [was freq_coeff_partial]
//   B: reduce chunk partials                          [was coeff_reduce]
//   C: rebuild low, fuse, single-pass LayerNorm       [was freq_ln_kernel]
// Rationale: measured 276.5us vs ~73us traffic roofline; all 3 old dispatches
// were individually <79us (below the 80us harness-fill top-k cutoff) => large
// inter-dispatch overhead + redundant coef re-reads. Fusing removes 2 launch
// boundaries, lets phase C amortize coefficients across 8 row-groups/block,
// and gives us a single >80us dispatch that will surface real counters.

constexpr int Sc = 2048;
constexpr int Hc = 1024;
constexpr int H4 = Hc / 4;           // float4s per row
constexpr int CKc = 64;              // phase-A chunks
constexpr int SCHUNK = Sc / CKc;     // 32 rows per chunk
constexpr float TWO_PI_OVER_S = 6.283185307179586f / (float)Sc;

typedef float nfloat4 __attribute__((ext_vector_type(4)));  // native vec for nontemporal builtin

__device__ __forceinline__ void sincos7(int s, float w[7]) {
    float sn1, cs1;
    sincosf(TWO_PI_OVER_S * (float)s, &sn1, &cs1);
    const float cs2 = fmaf(2.f * cs1, cs1, -1.f);
    const float sn2 = 2.f * sn1 * cs1;
    const float cs3 = cs1 * cs2 - sn1 * sn2;
    const float sn3 = sn1 * cs2 + cs1 * sn2;
    w[0] = 1.f; w[1] = cs1; w[2] = sn1; w[3] = cs2; w[4] = sn2; w[5] = cs3; w[6] = sn3;
}

// ---------------- fused single-launch kernel (cooperative) ----------------
__global__ __launch_bounds__(256, 4) void fused_freq_ln(
    const float* __restrict__ x, float* __restrict__ coefp,
    float* __restrict__ coef, const float* __restrict__ sqb,
    const float* __restrict__ gam, const float* __restrict__ lbeta,
    float* __restrict__ out, int B)
{
    const int tid  = threadIdx.x;
    const int nblk = gridDim.x;
    cg::grid_group grid = cg::this_grid();

    // ---------------- Phase A: partial projection sums ----------------
    const int nTaskA = CKc * B;                       // 1024 tasks at B=16
    for (int task = blockIdx.x; task < nTaskA; task += nblk) {
        const int b     = task / CKc;
        const int chunk = task - b * CKc;
        const int s0    = chunk * SCHUNK;
        const float4* __restrict__ xb =
            reinterpret_cast<const float4*>(x) + (size_t)b * Sc * H4 + tid;

        float acc[7][4];
#pragma unroll
        for (int j = 0; j < 7; ++j)
#pragma unroll
            for (int e = 0; e < 4; ++e) acc[j][e] = 0.f;

#pragma unroll 2
        for (int si = 0; si < SCHUNK; si += 4) {
            float4 v[4];
#pragma unroll
            for (int r = 0; r < 4; ++r)
                v[r] = xb[(size_t)(s0 + si + r) * H4];
#pragma unroll
            for (int r = 0; r < 4; ++r) {
                float w[7];
                sincos7(s0 + si + r, w);
                const float vv[4] = {v[r].x, v[r].y, v[r].z, v[r].w};
#pragma unroll
                for (int j = 0; j < 7; ++j)
#pragma unroll
                    for (int e = 0; e < 4; ++e)
                        acc[j][e] = fmaf(w[j], vv[e], acc[j][e]);
            }
        }

        float4* cp = reinterpret_cast<float4*>(coefp) +
                     ((size_t)chunk * B + b) * 7 * H4 + tid;
#pragma unroll
        for (int j = 0; j < 7; ++j) {
            float4 o = {acc[j][0], acc[j][1], acc[j][2], acc[j][3]};
            cp[(size_t)j * H4] = o;
        }
    }

    grid.sync();

    // ---------------- Phase B: reduce chunk partials ----------------
    const int n4 = B * 7 * H4;                        // 28672 float4 at B=16
    for (int i = blockIdx.x * 256 + tid; i < n4; i += nblk * 256) {
        const float4* __restrict__ p = reinterpret_cast<const float4*>(coefp) + i;
        float sx = 0.f, sy = 0.f, sz = 0.f, sw = 0.f;
#pragma unroll 8
        for (int c = 0; c < CKc; ++c) {
            const float4 v = p[(size_t)c * n4];
            sx += v.x; sy += v.y; sz += v.z; sw += v.w;
        }
        const float4 o = {sx, sy, sz, sw};
        reinterpret_cast<float4*>(coef)[i] = o;
    }

    grid.sync();

    // ---------------- Phase C: rebuild low + fused LayerNorm ----------------
    const float4 sb4 = reinterpret_cast<const float4*>(sqb)[tid];
    const float4 g4  = reinterpret_cast<const float4*>(gam)[tid];
    const float4 be4 = reinterpret_cast<const float4*>(lbeta)[tid];
    const float gg[4] = {g4.x, g4.y, g4.z, g4.w};
    const float be[4] = {be4.x, be4.y, be4.z, be4.w};
    float ap[4], am[4];
    {
        const float bbv[4] = {sb4.x, sb4.y, sb4.z, sb4.w};
#pragma unroll
        for (int e = 0; e < 4; ++e) {
            const float t = bbv[e] * bbv[e];
            ap[e] = 1.f + t;
            am[e] = (1.f - t) * (1.f / (float)Sc);
        }
    }

    __shared__ float smred[2][4][8];                  // parity double-buffer
    const int lane = tid & 63, wv = tid >> 6;

    const int nGroup = B * (Sc / 4);                  // 8192 groups of 4 rows
    const int tpb  = (nGroup + nblk - 1) / nblk;      // contiguous span/block
    const int gBeg = blockIdx.x * tpb;
    int gEnd = gBeg + tpb;
    if (gEnd > nGroup) gEnd = nGroup;

    int curb = -1;
    float cfx[7][4];                                  // am and x2 folded in
    int par = 0;
    for (int g = gBeg; g < gEnd; ++g, par ^= 1) {
        const int b  = g >> 9;                        // Sc/4 == 512 groups per b
        const int s0 = (g & 511) << 2;
        if (b != curb) {                              // coef load once per b-span
            curb = b;
            const float4* __restrict__ CF =
                reinterpret_cast<const float4*>(coef) + (size_t)b * 7 * H4 + tid;
#pragma unroll
            for (int j = 0; j < 7; ++j) {
                const float4 t = CF[(size_t)j * H4];
                const float sc = (j == 0) ? 1.f : 2.f;
                cfx[j][0] = t.x * am[0] * sc;
                cfx[j][1] = t.y * am[1] * sc;
                cfx[j][2] = t.z * am[2] * sc;
                cfx[j][3] = t.w * am[3] * sc;
            }
        }

        const size_t rowBase = ((size_t)b * Sc + s0) * H4 + tid;
        float4 xv[4];
#pragma unroll
        for (int r = 0; r < 4; ++r)
            xv[r] = reinterpret_cast<const float4*>(x)[rowBase + (size_t)r * H4];

        float y[4][4], s1[4], s2[4];
#pragma unroll
        for (int r = 0; r < 4; ++r) {
            float w[7];
            sincos7(s0 + r, w);
            const float xx[4] = {xv[r].x, xv[r].y, xv[r].z, xv[r].w};
            s1[r] = 0.f; s2[r] = 0.f;
#pragma unroll
            for (int e = 0; e < 4; ++e) {
                float lp = cfx[0][e];
#pragma unroll
                for (int j = 1; j < 7; ++j) lp = fmaf(cfx[j][e], w[j], lp);
                const float yy = fmaf(ap[e], xx[e], lp);
                y[r][e] = yy;
                s1[r] += yy;
                s2[r] = fmaf(yy, yy, s2[r]);
            }
        }

        // fused block reduction of (sum, sumsq) x 4 rows
#pragma unroll
        for (int off = 32; off > 0; off >>= 1) {
#pragma unroll
            for (int r = 0; r < 4; ++r) {
                s1[r] += __shfl_down(s1[r], off, 64);
                s2[r] += __shfl_down(s2[r], off, 64);
            }
        }
        if (lane == 0) {
#pragma unroll
            for (int r = 0; r < 4; ++r) {
                smred[par][wv][r]     = s1[r];
                smred[par][wv][4 + r] = s2[r];
            }
        }
        __syncthreads();

#pragma unroll
        for (int r = 0; r < 4; ++r) {
            const float m = (smred[par][0][r] + smred[par][1][r] +
                             smred[par][2][r] + smred[par][3][r]) * (1.f / (float)Hc);
            const float q = (smred[par][0][4+r] + smred[par][1][4+r] +
                             smred[par][2][4+r] + smred[par][3][4+r]) * (1.f / (float)Hc);
            const float inv = rsqrtf(fmaf(-m, m, q) + 1e-12f);
            nfloat4 o;
            o.x = fmaf((y[r][0] - m) * inv, gg[0], be[0]);
            o.y = fmaf((y[r][1] - m) * inv, gg[1], be[1]);
            o.z = fmaf((y[r][2] - m) * inv, gg[2], be[2]);
            o.w = fmaf((y[r][3] - m) * inv, gg[3], be[3]);
            __builtin_nontemporal_store(o, reinterpret_cast<nfloat4*>(out) + rowBase + (size_t)r * H4);
        }
    }
}

// ================= fallback: original 3-kernel path =================
__global__ __launch_bounds__(256) void freq_coeff_partial(
    const float* __restrict__ x, float* __restrict__ coefp,
    int B, int schunk) {
    const int tid   = threadIdx.x;
    const int b     = blockIdx.y;
    const int chunk = blockIdx.x;
    const int s0    = chunk * schunk;

    const float4* __restrict__ xb =
        reinterpret_cast<const float4*>(x) + (size_t)b * Sc * H4 + tid;

    float acc[7][4];
#pragma unroll
    for (int j = 0; j < 7; ++j)
#pragma unroll
        for (int e = 0; e < 4; ++e) acc[j][e] = 0.f;

    for (int si = 0; si < schunk; si += 4) {
        float4 v[4];
#pragma unroll
        for (int r = 0; r < 4; ++r)
            v[r] = xb[(size_t)(s0 + si + r) * H4];
#pragma unroll
        for (int r = 0; r < 4; ++r) {
            float w[7];
            sincos7(s0 + si + r, w);
            const float vv[4] = {v[r].x, v[r].y, v[r].z, v[r].w};
#pragma unroll
            for (int j = 0; j < 7; ++j)
#pragma unroll
                for (int e = 0; e < 4; ++e)
                    acc[j][e] = fmaf(w[j], vv[e], acc[j][e]);
        }
    }

    float4* cp = reinterpret_cast<float4*>(coefp) +
                 ((size_t)chunk * B + b) * 7 * H4 + tid;
#pragma unroll
    for (int j = 0; j < 7; ++j) {
        float4 o = {acc[j][0], acc[j][1], acc[j][2], acc[j][3]};
        cp[(size_t)j * H4] = o;
    }
}

__global__ __launch_bounds__(256) void coeff_reduce(
    const float* __restrict__ coefp, float* __restrict__ coef,
    int CK, int n4) {
    const int i = blockIdx.x * 256 + threadIdx.x;
    if (i >= n4) return;
    const float4* __restrict__ p = reinterpret_cast<const float4*>(coefp) + i;
    float4 s = {0.f, 0.f, 0.f, 0.f};
    for (int c = 0; c < CK; ++c) {
        const float4 v = p[(size_t)c * n4];
        s.x += v.x; s.y += v.y; s.z += v.z; s.w += v.w;
    }
    reinterpret_cast<float4*>(coef)[i] = s;
}

__global__ __launch_bounds__(256) void freq_ln_kernel(
    const float* __restrict__ x, const float* __restrict__ coef,
    const float* __restrict__ sqb, const float* __restrict__ gamma,
    const float* __restrict__ lbeta, float* __restrict__ out) {
    const int tid = threadIdx.x;
    const int b   = blockIdx.y;
    const int s0  = blockIdx.x * 4;
    const size_t rowBase = ((size_t)b * Sc + s0) * H4 + tid;

    const float4 sb4 = reinterpret_cast<const float4*>(sqb)[tid];
    const float4 g4  = reinterpret_cast<const float4*>(gamma)[tid];
    const float4 be4 = reinterpret_cast<const float4*>(lbeta)[tid];
    const float bb[4] = {sb4.x, sb4.y, sb4.z, sb4.w};
    const float gg[4] = {g4.x, g4.y, g4.z, g4.w};
    const float be[4] = {be4.x, be4.y, be4.z, be4.w};
    float ap[4], am[4];
#pragma unroll
    for (int e = 0; e < 4; ++e) {
        const float t = bb[e] * bb[e];
        ap[e] = 1.f + t;
        am[e] = (1.f - t) * (1.f / (float)Sc);
    }

    const float4* __restrict__ CF =
        reinterpret_cast<const float4*>(coef) + (size_t)b * 7 * H4 + tid;
    float cf[7][4];
#pragma unroll
    for (int j = 0; j < 7; ++j) {
        const float4 t = CF[(size_t)j * H4];
        cf[j][0] = t.x; cf[j][1] = t.y; cf[j][2] = t.z; cf[j][3] = t.w;
    }

    float4 xv[4];
#pragma unroll
    for (int r = 0; r < 4; ++r)
        xv[r] = reinterpret_cast<const float4*>(x)[rowBase + (size_t)r * H4];

    float y[4][4], s1[4], s2[4];
#pragma unroll
    for (int r = 0; r < 4; ++r) {
        float w[7];
        sincos7(s0 + r, w);
#pragma unroll
        for (int j = 1; j < 7; ++j) w[j] *= 2.f;
        const float xx[4] = {xv[r].x, xv[r].y, xv[r].z, xv[r].w};
        s1[r] = 0.f; s2[r] = 0.f;
#pragma unroll
        for (int e = 0; e < 4; ++e) {
            float lp = cf[0][e];
#pragma unroll
            for (int j = 1; j < 7; ++j) lp = fmaf(cf[j][e], w[j], lp);
            const float yy = fmaf(ap[e], xx[e], am[e] * lp);
            y[r][e] = yy;
            s1[r] += yy;
            s2[r] = fmaf(yy, yy, s2[r]);
        }
    }

    const int lane = tid & 63, wv = tid >> 6;
#pragma unroll
    for (int off = 32; off > 0; off >>= 1) {
#pragma unroll
        for (int r = 0; r < 4; ++r) {
            s1[r] += __shfl_down(s1[r], off, 64);
            s2[r] += __shfl_down(s2[r], off, 64);
        }
    }
    __shared__ float sm[4][8];
    if (lane == 0) {
#pragma unroll
        for (int r = 0; r < 4; ++r) { sm[wv][r] = s1[r]; sm[wv][4 + r] = s2[r]; }
    }
    __syncthreads();

#pragma unroll
    for (int r = 0; r < 4; ++r) {
        const float m  = (sm[0][r] + sm[1][r] + sm[2][r] + sm[3][r]) * (1.f / (float)Hc);
        const float q  = (sm[0][4 + r] + sm[1][4 + r] + sm[2][4 + r] + sm[3][4 + r]) * (1.f / (float)Hc);
        const float inv = rsqrtf(fmaf(-m, m, q) + 1e-12f);
        nfloat4 o;
        o.x = fmaf((y[r][0] - m) * inv, gg[0], be[0]);
        o.y = fmaf((y[r][1] - m) * inv, gg[1], be[1]);
        o.z = fmaf((y[r][2] - m) * inv, gg[2], be[2]);
        o.w = fmaf((y[r][3] - m) * inv, gg[3], be[3]);
        __builtin_nontemporal_store(o, reinterpret_cast<nfloat4*>(out) + rowBase + (size_t)r * H4);
    }
}

extern "C" void kernel_launch(void* const* d_in, const int* in_sizes, int n_in,
                              void* d_out, int out_size, void* d_ws, size_t ws_size,
                              hipStream_t stream) {
    const float* x     = (const float*)d_in[0];   // [B,S,H] f32
    const float* sqb   = (const float*)d_in[1];   // [H]
    const float* gamma = (const float*)d_in[2];   // [H]
    const float* lbeta = (const float*)d_in[3];   // [H]
    float* out = (float*)d_out;

    const int B = in_sizes[0] / (Sc * Hc);        // 16
    const size_t coefElems = (size_t)B * 7 * Hc;  // 114688
    const size_t coefBytes = coefElems * sizeof(float);

    // --- preferred path: single cooperative launch ---
    static int coopMax = -2;                      // -2 uninit, -1 unavailable
    if (coopMax == -2) {
        int dev = 0, nCU = 0, coop = 0, occ = 0;
        (void)hipGetDevice(&dev);
        (void)hipDeviceGetAttribute(&nCU, hipDeviceAttributeMultiprocessorCount, dev);
        (void)hipDeviceGetAttribute(&coop, hipDeviceAttributeCooperativeLaunch, dev);
        hipError_t oe = hipOccupancyMaxActiveBlocksPerMultiprocessor(
            &occ, fused_freq_ln, 256, 0);
        coopMax = (coop && oe == hipSuccess && occ > 0 && nCU > 0) ? occ * nCU : -1;
    }

    if (coopMax > 0 && (size_t)(CKc + 1) * coefBytes <= ws_size) {
        float* coefp = (float*)d_ws;                       // [CKc][B][7][H]
        float* coef  = coefp + (size_t)CKc * coefElems;    // [B][7][H]
        int grid = CKc * B;                                // 1024 phase-A tasks
        if (grid > coopMax) grid = coopMax;                // co-residency bound
        void* args[] = {(void*)&x, (void*)&coefp, (void*)&coef, (void*)&sqb,
                        (void*)&gamma, (void*)&lbeta, (void*)&out, (void*)&B};
        hipError_t e = hipLaunchCooperativeKernel((const void*)fused_freq_ln,
                                                  dim3(grid), dim3(256),
                                                  args, 0, stream);
        if (e == hipSuccess) return;
        (void)hipGetLastError();                  // clear, fall through
    }

    // --- fallback: original 3-kernel path ---
    int CK = 64;
    while (CK > 1 && (size_t)(CK + 1) * coefBytes > ws_size) CK >>= 1;

    float* coefp = (float*)d_ws;
    float* coef  = (CK == 1) ? coefp : coefp + CK * coefElems;

    const int schunk = Sc / CK;
    dim3 g1(CK, B);
    freq_coeff_partial<<<g1, 256, 0, stream>>>(x, coefp, B, schunk);

    if (CK > 1) {
        const int n4 = (int)(coefElems / 4);
        coeff_reduce<<<(n4 + 255) / 256, 256, 0, stream>>>(coefp, coef, CK, n4);
    }

    dim3 g2(Sc / 4, B);
    freq_ln_kernel<<<g2, 256, 0, stream>>>(x, coef, sqb, gamma, lbeta, out);
}

// Round 2
// 343.823 us; speedup vs baseline: 1.1329x; 1.1329x over previous
//
#include <hip/hip_runtime.h>

// B=16, S=2048, H=1024, C=4 kept rfft coeffs (ortho) == rank-7 projection:
//   a0 = sum_s x ; ak = sum_s x cos(2pi k s/S) ; bk = sum_s x sin(2pi k s/S), k=1..3
//   low[s] = (a0 + 2*sum_k(ak*cos + bk*sin)) / S
//   out = LayerNorm_H( (1+beta^2)*x + (1-beta^2)*low )
//
// v3: back to 3 graph-capturable dispatches (cooperative fusion measured 325us
// at 970 GB/s / 46% occ / 12% BW -- latency-bound, + ~64us capture-fallback
// launch tax). This version doubles pass-1 TLP (CK=128 -> 2048 blocks, 8/CU),
// quadruples reduce TLP (float-per-thread, 448 blocks), and keeps the proven
// 8192-block pass 2 with coefficient folding and x-loads issued first.

constexpr int Sc = 2048;
constexpr int Hc = 1024;
constexpr int H4 = Hc / 4;           // float4s per row
constexpr float TWO_PI_OVER_S = 6.283185307179586f / (float)Sc;

typedef float nfloat4 __attribute__((ext_vector_type(4)));  // native vec for nontemporal builtin

__device__ __forceinline__ void sincos7(int s, float w[7]) {
    float sn1, cs1;
    sincosf(TWO_PI_OVER_S * (float)s, &sn1, &cs1);
    const float cs2 = fmaf(2.f * cs1, cs1, -1.f);
    const float sn2 = 2.f * sn1 * cs1;
    const float cs3 = cs1 * cs2 - sn1 * sn2;
    const float sn3 = sn1 * cs2 + cs1 * sn2;
    w[0] = 1.f; w[1] = cs1; w[2] = sn1; w[3] = cs2; w[4] = sn2; w[5] = cs3; w[6] = sn3;
}

// ---------------- Pass 1: partial projection sums, no atomics ----------------
// grid (CK, B), 256 thr. CK=128 -> 2048 blocks = 8 blocks/CU (vs 4 before).
// launch_bounds(256,8) pins VGPR<=64 (fused build proved this fits in 56).
__global__ __launch_bounds__(256, 8) void freq_coeff_partial(
    const float* __restrict__ x, float* __restrict__ coefp,
    int B, int schunk) {
    const int tid   = threadIdx.x;        // 256 threads x float4 = all H
    const int b     = blockIdx.y;
    const int chunk = blockIdx.x;
    const int s0    = chunk * schunk;

    const float4* __restrict__ xb =
        reinterpret_cast<const float4*>(x) + (size_t)b * Sc * H4 + tid;

    float acc[7][4];
#pragma unroll
    for (int j = 0; j < 7; ++j)
#pragma unroll
        for (int e = 0; e < 4; ++e) acc[j][e] = 0.f;

    for (int si = 0; si < schunk; si += 4) {
        float4 v[4];
#pragma unroll
        for (int r = 0; r < 4; ++r)
            v[r] = xb[(size_t)(s0 + si + r) * H4];
#pragma unroll
        for (int r = 0; r < 4; ++r) {
            float w[7];
            sincos7(s0 + si + r, w);
            const float vv[4] = {v[r].x, v[r].y, v[r].z, v[r].w};
#pragma unroll
            for (int j = 0; j < 7; ++j)
#pragma unroll
                for (int e = 0; e < 4; ++e)
                    acc[j][e] = fmaf(w[j], vv[e], acc[j][e]);
        }
    }

    float4* cp = reinterpret_cast<float4*>(coefp) +
                 ((size_t)chunk * B + b) * 7 * H4 + tid;
#pragma unroll
    for (int j = 0; j < 7; ++j) {
        float4 o = {acc[j][0], acc[j][1], acc[j][2], acc[j][3]};
        cp[(size_t)j * H4] = o;
    }
}

// ---------------- Pass 1.5: reduce chunk partials ----------------
// float-per-thread: n = B*7*H = 114688 -> 448 blocks (vs 112 float4 blocks
// before, which left most of the chip idle). unroll 8 = 8 outstanding loads.
__global__ __launch_bounds__(256, 8) void coeff_reduce(
    const float* __restrict__ coefp, float* __restrict__ coef,
    int CK, int n) {
    const int i = blockIdx.x * 256 + threadIdx.x;   // float index into [B*7*H]
    if (i >= n) return;
    const float* __restrict__ p = coefp + i;
    float s = 0.f;
#pragma unroll 8
    for (int c = 0; c < CK; ++c) s += p[(size_t)c * n];
    coef[i] = s;
}

// ---------------- Pass 2: 4 rows per block, fused LN ----------------
__global__ __launch_bounds__(256, 8) void freq_ln_kernel(
    const float* __restrict__ x, const float* __restrict__ coef,
    const float* __restrict__ sqb, const float* __restrict__ gamma,
    const float* __restrict__ lbeta, float* __restrict__ out) {
    const int tid = threadIdx.x;
    const int b   = blockIdx.y;
    const int s0  = blockIdx.x * 4;
    const size_t rowBase = ((size_t)b * Sc + s0) * H4 + tid;

    // x rows first: longest-latency independent loads go out early
    float4 xv[4];
#pragma unroll
    for (int r = 0; r < 4; ++r)
        xv[r] = reinterpret_cast<const float4*>(x)[rowBase + (size_t)r * H4];

    // params (L2/L3 resident)
    const float4 sb4 = reinterpret_cast<const float4*>(sqb)[tid];
    const float4 g4  = reinterpret_cast<const float4*>(gamma)[tid];
    const float4 be4 = reinterpret_cast<const float4*>(lbeta)[tid];
    const float gg[4] = {g4.x, g4.y, g4.z, g4.w};
    const float be[4] = {be4.x, be4.y, be4.z, be4.w};
    float ap[4], am[4];
    {
        const float bb[4] = {sb4.x, sb4.y, sb4.z, sb4.w};
#pragma unroll
        for (int e = 0; e < 4; ++e) {
            const float t = bb[e] * bb[e];
            ap[e] = 1.f + t;
            am[e] = (1.f - t) * (1.f / (float)Sc);
        }
    }

    // coefficients for this b; fold am and the x2 harmonic factor in
    const float4* __restrict__ CF =
        reinterpret_cast<const float4*>(coef) + (size_t)b * 7 * H4 + tid;
    float cfx[7][4];
#pragma unroll
    for (int j = 0; j < 7; ++j) {
        const float4 t = CF[(size_t)j * H4];
        const float sc = (j == 0) ? 1.f : 2.f;
        cfx[j][0] = t.x * am[0] * sc;
        cfx[j][1] = t.y * am[1] * sc;
        cfx[j][2] = t.z * am[2] * sc;
        cfx[j][3] = t.w * am[3] * sc;
    }

    float y[4][4], s1[4], s2[4];
#pragma unroll
    for (int r = 0; r < 4; ++r) {
        float w[7];
        sincos7(s0 + r, w);
        const float xx[4] = {xv[r].x, xv[r].y, xv[r].z, xv[r].w};
        s1[r] = 0.f; s2[r] = 0.f;
#pragma unroll
        for (int e = 0; e < 4; ++e) {
            float lp = cfx[0][e];
#pragma unroll
            for (int j = 1; j < 7; ++j) lp = fmaf(cfx[j][e], w[j], lp);
            const float yy = fmaf(ap[e], xx[e], lp);
            y[r][e] = yy;
            s1[r] += yy;
            s2[r] = fmaf(yy, yy, s2[r]);
        }
    }

    // fused block reduction of (sum, sumsq) x 4 rows
    const int lane = tid & 63, wv = tid >> 6;
#pragma unroll
    for (int off = 32; off > 0; off >>= 1) {
#pragma unroll
        for (int r = 0; r < 4; ++r) {
            s1[r] += __shfl_down(s1[r], off, 64);
            s2[r] += __shfl_down(s2[r], off, 64);
        }
    }
    __shared__ float sm[4][8];
    if (lane == 0) {
#pragma unroll
        for (int r = 0; r < 4; ++r) { sm[wv][r] = s1[r]; sm[wv][4 + r] = s2[r]; }
    }
    __syncthreads();

#pragma unroll
    for (int r = 0; r < 4; ++r) {
        const float m  = (sm[0][r] + sm[1][r] + sm[2][r] + sm[3][r]) * (1.f / (float)Hc);
        const float q  = (sm[0][4 + r] + sm[1][4 + r] + sm[2][4 + r] + sm[3][4 + r]) * (1.f / (float)Hc);
        const float inv = rsqrtf(fmaf(-m, m, q) + 1e-12f);
        nfloat4 o;
        o.x = fmaf((y[r][0] - m) * inv, gg[0], be[0]);
        o.y = fmaf((y[r][1] - m) * inv, gg[1], be[1]);
        o.z = fmaf((y[r][2] - m) * inv, gg[2], be[2]);
        o.w = fmaf((y[r][3] - m) * inv, gg[3], be[3]);
        __builtin_nontemporal_store(o, reinterpret_cast<nfloat4*>(out) + rowBase + (size_t)r * H4);
    }
}

extern "C" void kernel_launch(void* const* d_in, const int* in_sizes, int n_in,
                              void* d_out, int out_size, void* d_ws, size_t ws_size,
                              hipStream_t stream) {
    const float* x     = (const float*)d_in[0];   // [B,S,H] f32
    const float* sqb   = (const float*)d_in[1];   // [H]
    const float* gamma = (const float*)d_in[2];   // [H]
    const float* lbeta = (const float*)d_in[3];   // [H]
    float* out = (float*)d_out;

    const int B = in_sizes[0] / (Sc * Hc);        // 16
    const size_t coefElems = (size_t)B * 7 * Hc;  // 114688
    const size_t coefBytes = coefElems * sizeof(float);

    // CK=128 -> 2048 pass-1 blocks (8/CU). Halve if workspace is tight.
    int CK = 128;
    while (CK > 1 && (size_t)(CK + 1) * coefBytes > ws_size) CK >>= 1;

    float* coefp = (float*)d_ws;                          // [CK][B][7][H]
    float* coef  = (CK == 1) ? coefp : coefp + (size_t)CK * coefElems;

    const int schunk = Sc / CK;                           // rows per pass-1 block
    dim3 g1(CK, B);
    freq_coeff_partial<<<g1, 256, 0, stream>>>(x, coefp, B, schunk);

    if (CK > 1) {
        const int n = (int)coefElems;                     // 114688 floats
        coeff_reduce<<<(n + 255) / 256, 256, 0, stream>>>(coefp, coef, CK, n);
    }

    dim3 g2(Sc / 4, B);
    freq_ln_kernel<<<g2, 256, 0, stream>>>(x, coef, sqb, gamma, lbeta, out);
}

// Round 3
// 272.822 us; speedup vs baseline: 1.4278x; 1.2602x over previous
//
#include <hip/hip_runtime.h>

// B=16, S=2048, H=1024, C=4 kept rfft coeffs (ortho) == rank-7 projection:
//   a0 = sum_s x ; ak = sum_s x cos(2pi k s/S) ; bk = sum_s x sin(2pi k s/S), k=1..3
//   low[s] = (a0 + 2*sum_k(ak*cos + bk*sin)) / S
//   out = LayerNorm_H( (1+beta^2)*x + (1-beta^2)*low )
//
// v4: v3 minus the register caps. Round-2 counters showed the smoking gun:
// freq_ln_kernel at VGPR_Count=32 under __launch_bounds__(256,8) was SPILLING
// (WRITE_SIZE 360MB vs 134MB ideal out, dur 115us, VALUBusy 20%). The (256,8)
// caps traded registers for waves and lost. Plain (256) restores v1's no-spill
// codegen; CK=128 pass-1 grid and float-per-thread reduce are kept.

constexpr int Sc = 2048;
constexpr int Hc = 1024;
constexpr int H4 = Hc / 4;           // float4s per row
constexpr float TWO_PI_OVER_S = 6.283185307179586f / (float)Sc;

typedef float nfloat4 __attribute__((ext_vector_type(4)));  // native vec for nontemporal builtin

__device__ __forceinline__ void sincos7(int s, float w[7]) {
    float sn1, cs1;
    sincosf(TWO_PI_OVER_S * (float)s, &sn1, &cs1);
    const float cs2 = fmaf(2.f * cs1, cs1, -1.f);
    const float sn2 = 2.f * sn1 * cs1;
    const float cs3 = cs1 * cs2 - sn1 * sn2;
    const float sn3 = sn1 * cs2 + cs1 * sn2;
    w[0] = 1.f; w[1] = cs1; w[2] = sn1; w[3] = cs2; w[4] = sn2; w[5] = cs3; w[6] = sn3;
}

// ---------------- Pass 1: partial projection sums, no atomics ----------------
// grid (CK, B), 256 thr. CK=128 -> 2048 blocks. NO register cap: acc[7][4]+v[4]
// needs ~60 VGPRs; capping to 64 (v3) risked spill/remat. VGPR ~60 still
// admits 8 waves/EU naturally.
__global__ __launch_bounds__(256) void freq_coeff_partial(
    const float* __restrict__ x, float* __restrict__ coefp,
    int B, int schunk) {
    const int tid   = threadIdx.x;        // 256 threads x float4 = all H
    const int b     = blockIdx.y;
    const int chunk = blockIdx.x;
    const int s0    = chunk * schunk;

    const float4* __restrict__ xb =
        reinterpret_cast<const float4*>(x) + (size_t)b * Sc * H4 + tid;

    float acc[7][4];
#pragma unroll
    for (int j = 0; j < 7; ++j)
#pragma unroll
        for (int e = 0; e < 4; ++e) acc[j][e] = 0.f;

    for (int si = 0; si < schunk; si += 4) {
        float4 v[4];
#pragma unroll
        for (int r = 0; r < 4; ++r)
            v[r] = xb[(size_t)(s0 + si + r) * H4];
#pragma unroll
        for (int r = 0; r < 4; ++r) {
            float w[7];
            sincos7(s0 + si + r, w);
            const float vv[4] = {v[r].x, v[r].y, v[r].z, v[r].w};
#pragma unroll
            for (int j = 0; j < 7; ++j)
#pragma unroll
                for (int e = 0; e < 4; ++e)
                    acc[j][e] = fmaf(w[j], vv[e], acc[j][e]);
        }
    }

    float4* cp = reinterpret_cast<float4*>(coefp) +
                 ((size_t)chunk * B + b) * 7 * H4 + tid;
#pragma unroll
    for (int j = 0; j < 7; ++j) {
        float4 o = {acc[j][0], acc[j][1], acc[j][2], acc[j][3]};
        cp[(size_t)j * H4] = o;
    }
}

// ---------------- Pass 1.5: reduce chunk partials ----------------
// float-per-thread: n = B*7*H = 114688 -> 448 blocks; unroll 8 outstanding loads.
__global__ __launch_bounds__(256) void coeff_reduce(
    const float* __restrict__ coefp, float* __restrict__ coef,
    int CK, int n) {
    const int i = blockIdx.x * 256 + threadIdx.x;   // float index into [B*7*H]
    if (i >= n) return;
    const float* __restrict__ p = coefp + i;
    float s = 0.f;
#pragma unroll 8
    for (int c = 0; c < CK; ++c) s += p[(size_t)c * n];
    coef[i] = s;
}

// ---------------- Pass 2: 4 rows per block, fused LN ----------------
// Plain (256): needs y[4][4]+xv[4]+cfx[7][4]+params live; v3's (256,8) cap
// produced VGPR=32 + scratch spill (+226MB HBM writes). Never cap this one.
__global__ __launch_bounds__(256) void freq_ln_kernel(
    const float* __restrict__ x, const float* __restrict__ coef,
    const float* __restrict__ sqb, const float* __restrict__ gamma,
    const float* __restrict__ lbeta, float* __restrict__ out) {
    const int tid = threadIdx.x;
    const int b   = blockIdx.y;
    const int s0  = blockIdx.x * 4;
    const size_t rowBase = ((size_t)b * Sc + s0) * H4 + tid;

    // x rows first: longest-latency independent loads go out early
    float4 xv[4];
#pragma unroll
    for (int r = 0; r < 4; ++r)
        xv[r] = reinterpret_cast<const float4*>(x)[rowBase + (size_t)r * H4];

    // params (L2/L3 resident)
    const float4 sb4 = reinterpret_cast<const float4*>(sqb)[tid];
    const float4 g4  = reinterpret_cast<const float4*>(gamma)[tid];
    const float4 be4 = reinterpret_cast<const float4*>(lbeta)[tid];
    const float gg[4] = {g4.x, g4.y, g4.z, g4.w};
    const float be[4] = {be4.x, be4.y, be4.z, be4.w};
    float ap[4], am[4];
    {
        const float bb[4] = {sb4.x, sb4.y, sb4.z, sb4.w};
#pragma unroll
        for (int e = 0; e < 4; ++e) {
            const float t = bb[e] * bb[e];
            ap[e] = 1.f + t;
            am[e] = (1.f - t) * (1.f / (float)Sc);
        }
    }

    // coefficients for this b; fold am and the x2 harmonic factor in
    const float4* __restrict__ CF =
        reinterpret_cast<const float4*>(coef) + (size_t)b * 7 * H4 + tid;
    float cfx[7][4];
#pragma unroll
    for (int j = 0; j < 7; ++j) {
        const float4 t = CF[(size_t)j * H4];
        const float sc = (j == 0) ? 1.f : 2.f;
        cfx[j][0] = t.x * am[0] * sc;
        cfx[j][1] = t.y * am[1] * sc;
        cfx[j][2] = t.z * am[2] * sc;
        cfx[j][3] = t.w * am[3] * sc;
    }

    float y[4][4], s1[4], s2[4];
#pragma unroll
    for (int r = 0; r < 4; ++r) {
        float w[7];
        sincos7(s0 + r, w);
        const float xx[4] = {xv[r].x, xv[r].y, xv[r].z, xv[r].w};
        s1[r] = 0.f; s2[r] = 0.f;
#pragma unroll
        for (int e = 0; e < 4; ++e) {
            float lp = cfx[0][e];
#pragma unroll
            for (int j = 1; j < 7; ++j) lp = fmaf(cfx[j][e], w[j], lp);
            const float yy = fmaf(ap[e], xx[e], lp);
            y[r][e] = yy;
            s1[r] += yy;
            s2[r] = fmaf(yy, yy, s2[r]);
        }
    }

    // fused block reduction of (sum, sumsq) x 4 rows
    const int lane = tid & 63, wv = tid >> 6;
#pragma unroll
    for (int off = 32; off > 0; off >>= 1) {
#pragma unroll
        for (int r = 0; r < 4; ++r) {
            s1[r] += __shfl_down(s1[r], off, 64);
            s2[r] += __shfl_down(s2[r], off, 64);
        }
    }
    __shared__ float sm[4][8];
    if (lane == 0) {
#pragma unroll
        for (int r = 0; r < 4; ++r) { sm[wv][r] = s1[r]; sm[wv][4 + r] = s2[r]; }
    }
    __syncthreads();

#pragma unroll
    for (int r = 0; r < 4; ++r) {
        const float m  = (sm[0][r] + sm[1][r] + sm[2][r] + sm[3][r]) * (1.f / (float)Hc);
        const float q  = (sm[0][4 + r] + sm[1][4 + r] + sm[2][4 + r] + sm[3][4 + r]) * (1.f / (float)Hc);
        const float inv = rsqrtf(fmaf(-m, m, q) + 1e-12f);
        nfloat4 o;
        o.x = fmaf((y[r][0] - m) * inv, gg[0], be[0]);
        o.y = fmaf((y[r][1] - m) * inv, gg[1], be[1]);
        o.z = fmaf((y[r][2] - m) * inv, gg[2], be[2]);
        o.w = fmaf((y[r][3] - m) * inv, gg[3], be[3]);
        __builtin_nontemporal_store(o, reinterpret_cast<nfloat4*>(out) + rowBase + (size_t)r * H4);
    }
}

extern "C" void kernel_launch(void* const* d_in, const int* in_sizes, int n_in,
                              void* d_out, int out_size, void* d_ws, size_t ws_size,
                              hipStream_t stream) {
    const float* x     = (const float*)d_in[0];   // [B,S,H] f32
    const float* sqb   = (const float*)d_in[1];   // [H]
    const float* gamma = (const float*)d_in[2];   // [H]
    const float* lbeta = (const float*)d_in[3];   // [H]
    float* out = (float*)d_out;

    const int B = in_sizes[0] / (Sc * Hc);        // 16
    const size_t coefElems = (size_t)B * 7 * Hc;  // 114688
    const size_t coefBytes = coefElems * sizeof(float);

    // CK=128 -> 2048 pass-1 blocks. Halve if workspace is tight.
    int CK = 128;
    while (CK > 1 && (size_t)(CK + 1) * coefBytes > ws_size) CK >>= 1;

    float* coefp = (float*)d_ws;                          // [CK][B][7][H]
    float* coef  = (CK == 1) ? coefp : coefp + (size_t)CK * coefElems;

    const int schunk = Sc / CK;                           // rows per pass-1 block
    dim3 g1(CK, B);
    freq_coeff_partial<<<g1, 256, 0, stream>>>(x, coefp, B, schunk);

    if (CK > 1) {
        const int n = (int)coefElems;                     // 114688 floats
        coeff_reduce<<<(n + 255) / 256, 256, 0, stream>>>(coefp, coef, CK, n);
    }

    dim3 g2(Sc / 4, B);
    freq_ln_kernel<<<g2, 256, 0, stream>>>(x, coef, sqb, gamma, lbeta, out);
}

// Round 4
// 258.215 us; speedup vs baseline: 1.5086x; 1.0566x over previous
//
#include <hip/hip_runtime.h>

// B=16, S=2048, H=1024, C=4 kept rfft coeffs (ortho) == rank-7 projection:
//   a0 = sum_s x ; ak = sum_s x cos(2pi k s/S) ; bk = sum_s x sin(2pi k s/S), k=1..3
//   low[s] = (a0 + 2*sum_k(ak*cos + bk*sin)) / S
//   out = LayerNorm_H( (1+beta^2)*x + (1-beta^2)*low )
//
// v5: v4 with CK 128->32. Accounting across rounds 0-3 shows ~160us/iter of
// harness workspace-poison fills (two 512MiB fillBufferAligned) inside the
// timed region; our controllable 3-kernel time is only ~110us vs ~90us traffic
// ideal. The biggest controllable fat is the CK=128 partial round-trip
// (57MB+57MB = ~19us of BW). CK=32 keeps 2 blocks/CU in pass 1 (32KB in
// flight/CU vs ~9.4KB needed to sustain HBM rate at ~900cy latency) while
// cutting partial traffic 4x. Pass 2 (no reg cap, proven no-spill) untouched.

constexpr int Sc = 2048;
constexpr int Hc = 1024;
constexpr int H4 = Hc / 4;           // float4s per row
constexpr float TWO_PI_OVER_S = 6.283185307179586f / (float)Sc;

typedef float nfloat4 __attribute__((ext_vector_type(4)));  // native vec for nontemporal builtin

__device__ __forceinline__ void sincos7(int s, float w[7]) {
    float sn1, cs1;
    sincosf(TWO_PI_OVER_S * (float)s, &sn1, &cs1);
    const float cs2 = fmaf(2.f * cs1, cs1, -1.f);
    const float sn2 = 2.f * sn1 * cs1;
    const float cs3 = cs1 * cs2 - sn1 * sn2;
    const float sn3 = sn1 * cs2 + cs1 * sn2;
    w[0] = 1.f; w[1] = cs1; w[2] = sn1; w[3] = cs2; w[4] = sn2; w[5] = cs3; w[6] = sn3;
}

// ---------------- Pass 1: partial projection sums, no atomics ----------------
// grid (CK, B), 256 thr. CK=32 -> 512 blocks (2/CU, 8 waves/CU); each wave
// keeps 4 outstanding 1KB loads -> 32KB in flight/CU, 3x the ~9.4KB needed to
// sustain ~10.4 B/cyc/CU HBM rate at ~900cy latency. NO register cap (v3's
// (256,8) cap caused scratch spill).
__global__ __launch_bounds__(256) void freq_coeff_partial(
    const float* __restrict__ x, float* __restrict__ coefp,
    int B, int schunk) {
    const int tid   = threadIdx.x;        // 256 threads x float4 = all H
    const int b     = blockIdx.y;
    const int chunk = blockIdx.x;
    const int s0    = chunk * schunk;

    const float4* __restrict__ xb =
        reinterpret_cast<const float4*>(x) + (size_t)b * Sc * H4 + tid;

    float acc[7][4];
#pragma unroll
    for (int j = 0; j < 7; ++j)
#pragma unroll
        for (int e = 0; e < 4; ++e) acc[j][e] = 0.f;

    for (int si = 0; si < schunk; si += 4) {
        float4 v[4];
#pragma unroll
        for (int r = 0; r < 4; ++r)
            v[r] = xb[(size_t)(s0 + si + r) * H4];
#pragma unroll
        for (int r = 0; r < 4; ++r) {
            float w[7];
            sincos7(s0 + si + r, w);
            const float vv[4] = {v[r].x, v[r].y, v[r].z, v[r].w};
#pragma unroll
            for (int j = 0; j < 7; ++j)
#pragma unroll
                for (int e = 0; e < 4; ++e)
                    acc[j][e] = fmaf(w[j], vv[e], acc[j][e]);
        }
    }

    float4* cp = reinterpret_cast<float4*>(coefp) +
                 ((size_t)chunk * B + b) * 7 * H4 + tid;
#pragma unroll
    for (int j = 0; j < 7; ++j) {
        float4 o = {acc[j][0], acc[j][1], acc[j][2], acc[j][3]};
        cp[(size_t)j * H4] = o;
    }
}

// ---------------- Pass 1.5: reduce chunk partials ----------------
// float-per-thread: n = B*7*H = 114688 -> 448 blocks; partials are L3-hot
// (just written), so this is a few us at CK=32.
__global__ __launch_bounds__(256) void coeff_reduce(
    const float* __restrict__ coefp, float* __restrict__ coef,
    int CK, int n) {
    const int i = blockIdx.x * 256 + threadIdx.x;   // float index into [B*7*H]
    if (i >= n) return;
    const float* __restrict__ p = coefp + i;
    float s = 0.f;
#pragma unroll 8
    for (int c = 0; c < CK; ++c) s += p[(size_t)c * n];
    coef[i] = s;
}

// ---------------- Pass 2: 4 rows per block, fused LN ----------------
// Plain (256): needs y[4][4]+xv[4]+cfx[7][4]+params live; v3's (256,8) cap
// produced VGPR=32 + scratch spill (+226MB HBM writes). Never cap this one.
__global__ __launch_bounds__(256) void freq_ln_kernel(
    const float* __restrict__ x, const float* __restrict__ coef,
    const float* __restrict__ sqb, const float* __restrict__ gamma,
    const float* __restrict__ lbeta, float* __restrict__ out) {
    const int tid = threadIdx.x;
    const int b   = blockIdx.y;
    const int s0  = blockIdx.x * 4;
    const size_t rowBase = ((size_t)b * Sc + s0) * H4 + tid;

    // x rows first: longest-latency independent loads go out early
    float4 xv[4];
#pragma unroll
    for (int r = 0; r < 4; ++r)
        xv[r] = reinterpret_cast<const float4*>(x)[rowBase + (size_t)r * H4];

    // params (L2/L3 resident)
    const float4 sb4 = reinterpret_cast<const float4*>(sqb)[tid];
    const float4 g4  = reinterpret_cast<const float4*>(gamma)[tid];
    const float4 be4 = reinterpret_cast<const float4*>(lbeta)[tid];
    const float gg[4] = {g4.x, g4.y, g4.z, g4.w};
    const float be[4] = {be4.x, be4.y, be4.z, be4.w};
    float ap[4], am[4];
    {
        const float bb[4] = {sb4.x, sb4.y, sb4.z, sb4.w};
#pragma unroll
        for (int e = 0; e < 4; ++e) {
            const float t = bb[e] * bb[e];
            ap[e] = 1.f + t;
            am[e] = (1.f - t) * (1.f / (float)Sc);
        }
    }

    // coefficients for this b; fold am and the x2 harmonic factor in
    const float4* __restrict__ CF =
        reinterpret_cast<const float4*>(coef) + (size_t)b * 7 * H4 + tid;
    float cfx[7][4];
#pragma unroll
    for (int j = 0; j < 7; ++j) {
        const float4 t = CF[(size_t)j * H4];
        const float sc = (j == 0) ? 1.f : 2.f;
        cfx[j][0] = t.x * am[0] * sc;
        cfx[j][1] = t.y * am[1] * sc;
        cfx[j][2] = t.z * am[2] * sc;
        cfx[j][3] = t.w * am[3] * sc;
    }

    float y[4][4], s1[4], s2[4];
#pragma unroll
    for (int r = 0; r < 4; ++r) {
        float w[7];
        sincos7(s0 + r, w);
        const float xx[4] = {xv[r].x, xv[r].y, xv[r].z, xv[r].w};
        s1[r] = 0.f; s2[r] = 0.f;
#pragma unroll
        for (int e = 0; e < 4; ++e) {
            float lp = cfx[0][e];
#pragma unroll
            for (int j = 1; j < 7; ++j) lp = fmaf(cfx[j][e], w[j], lp);
            const float yy = fmaf(ap[e], xx[e], lp);
            y[r][e] = yy;
            s1[r] += yy;
            s2[r] = fmaf(yy, yy, s2[r]);
        }
    }

    // fused block reduction of (sum, sumsq) x 4 rows
    const int lane = tid & 63, wv = tid >> 6;
#pragma unroll
    for (int off = 32; off > 0; off >>= 1) {
#pragma unroll
        for (int r = 0; r < 4; ++r) {
            s1[r] += __shfl_down(s1[r], off, 64);
            s2[r] += __shfl_down(s2[r], off, 64);
        }
    }
    __shared__ float sm[4][8];
    if (lane == 0) {
#pragma unroll
        for (int r = 0; r < 4; ++r) { sm[wv][r] = s1[r]; sm[wv][4 + r] = s2[r]; }
    }
    __syncthreads();

#pragma unroll
    for (int r = 0; r < 4; ++r) {
        const float m  = (sm[0][r] + sm[1][r] + sm[2][r] + sm[3][r]) * (1.f / (float)Hc);
        const float q  = (sm[0][4 + r] + sm[1][4 + r] + sm[2][4 + r] + sm[3][4 + r]) * (1.f / (float)Hc);
        const float inv = rsqrtf(fmaf(-m, m, q) + 1e-12f);
        nfloat4 o;
        o.x = fmaf((y[r][0] - m) * inv, gg[0], be[0]);
        o.y = fmaf((y[r][1] - m) * inv, gg[1], be[1]);
        o.z = fmaf((y[r][2] - m) * inv, gg[2], be[2]);
        o.w = fmaf((y[r][3] - m) * inv, gg[3], be[3]);
        __builtin_nontemporal_store(o, reinterpret_cast<nfloat4*>(out) + rowBase + (size_t)r * H4);
    }
}

extern "C" void kernel_launch(void* const* d_in, const int* in_sizes, int n_in,
                              void* d_out, int out_size, void* d_ws, size_t ws_size,
                              hipStream_t stream) {
    const float* x     = (const float*)d_in[0];   // [B,S,H] f32
    const float* sqb   = (const float*)d_in[1];   // [H]
    const float* gamma = (const float*)d_in[2];   // [H]
    const float* lbeta = (const float*)d_in[3];   // [H]
    float* out = (float*)d_out;

    const int B = in_sizes[0] / (Sc * Hc);        // 16
    const size_t coefElems = (size_t)B * 7 * Hc;  // 114688
    const size_t coefBytes = coefElems * sizeof(float);

    // CK=32: 512 pass-1 blocks (2/CU), partial round-trip only 2x14.7MB.
    int CK = 32;
    while (CK > 1 && (size_t)(CK + 1) * coefBytes > ws_size) CK >>= 1;

    float* coefp = (float*)d_ws;                          // [CK][B][7][H]
    float* coef  = (CK == 1) ? coefp : coefp + (size_t)CK * coefElems;

    const int schunk = Sc / CK;                           // rows per pass-1 block
    dim3 g1(CK, B);
    freq_coeff_partial<<<g1, 256, 0, stream>>>(x, coefp, B, schunk);

    if (CK > 1) {
        const int n = (int)coefElems;                     // 114688 floats
        coeff_reduce<<<(n + 255) / 256, 256, 0, stream>>>(coefp, coef, CK, n);
    }

    dim3 g2(Sc / 4, B);
    freq_ln_kernel<<<g2, 256, 0, stream>>>(x, coef, sqb, gamma, lbeta, out);
}